// Round 1
// baseline (1497.559 us; speedup 1.0000x reference)
//
#include <hip/hip_runtime.h>
#include <math.h>

#define CDIM 256
#define NPIX 4096
#define BATCH 4

// ---------------------------------------------------------------------------
// Projection: dst[b][o][n] = relu(scale[o] * sum_c W[o][c] x[b][c][n] + bias[o])
// grid (N/64, C/64, 3*B), block 256. Tile 64(o) x 64(n), K-chunk 32.
// ---------------------------------------------------------------------------
__global__ __launch_bounds__(256) void proj_kernel(
    const float* __restrict__ qf, const float* __restrict__ kf,
    const float* __restrict__ Wq, const float* __restrict__ Wk, const float* __restrict__ Wv,
    const float* __restrict__ sq, const float* __restrict__ bq,
    const float* __restrict__ sk, const float* __restrict__ bk,
    const float* __restrict__ sv, const float* __restrict__ bv,
    float* __restrict__ Q, float* __restrict__ K, float* __restrict__ V)
{
    const int n0 = blockIdx.x * 64;
    const int o0 = blockIdx.y * 64;
    const int z  = blockIdx.z;
    const int which = z % 3;   // 0=Q (from qf), 1=K (from kf), 2=V (from kf)
    const int b     = z / 3;

    const float* W; const float* x; const float* sc; const float* bi; float* dst;
    if (which == 0)      { W = Wq; x = qf; sc = sq; bi = bq; dst = Q; }
    else if (which == 1) { W = Wk; x = kf; sc = sk; bi = bk; dst = K; }
    else                 { W = Wv; x = kf; sc = sv; bi = bv; dst = V; }

    __shared__ float Wt[32][68];   // [c-chunk][o], transposed store
    __shared__ float Xt[32][68];   // [c-chunk][n]

    const int t  = threadIdx.x;
    const int to = t >> 4;         // 0..15 -> o rows 4*to..4*to+3
    const int tn = t & 15;         // 0..15 -> n cols 4*tn..4*tn+3

    const int w_oi  = t >> 2;          // 0..63
    const int w_cc0 = (t & 3) * 8;     // 0,8,16,24
    const int x_ci  = t >> 3;          // 0..31
    const int x_no  = (t & 7) * 8;     // 0..56

    float acc[4][4];
#pragma unroll
    for (int i = 0; i < 4; ++i)
#pragma unroll
        for (int j = 0; j < 4; ++j) acc[i][j] = 0.f;

    for (int c0 = 0; c0 < CDIM; c0 += 32) {
        // stage W tile (transposed) and x tile; leading sync protects prev compute
        float4 wv[2], xv[2];
#pragma unroll
        for (int v = 0; v < 2; ++v)
            wv[v] = *reinterpret_cast<const float4*>(
                &W[(size_t)(o0 + w_oi) * CDIM + c0 + w_cc0 + 4 * v]);
#pragma unroll
        for (int v = 0; v < 2; ++v)
            xv[v] = *reinterpret_cast<const float4*>(
                &x[((size_t)(b * CDIM + c0 + x_ci)) * NPIX + n0 + x_no + 4 * v]);
        __syncthreads();
#pragma unroll
        for (int v = 0; v < 2; ++v) {
            Wt[w_cc0 + 4 * v + 0][w_oi] = wv[v].x;
            Wt[w_cc0 + 4 * v + 1][w_oi] = wv[v].y;
            Wt[w_cc0 + 4 * v + 2][w_oi] = wv[v].z;
            Wt[w_cc0 + 4 * v + 3][w_oi] = wv[v].w;
            *reinterpret_cast<float4*>(&Xt[x_ci][x_no + 4 * v]) = xv[v];
        }
        __syncthreads();
#pragma unroll
        for (int cc = 0; cc < 32; ++cc) {
            float4 a = *reinterpret_cast<const float4*>(&Wt[cc][4 * to]);
            float4 c = *reinterpret_cast<const float4*>(&Xt[cc][4 * tn]);
            float wa[4] = {a.x, a.y, a.z, a.w};
            float xa[4] = {c.x, c.y, c.z, c.w};
#pragma unroll
            for (int i = 0; i < 4; ++i)
#pragma unroll
                for (int j = 0; j < 4; ++j)
                    acc[i][j] = fmaf(wa[i], xa[j], acc[i][j]);
        }
        __syncthreads();
    }

#pragma unroll
    for (int i = 0; i < 4; ++i) {
        const int o = o0 + 4 * to + i;
        const float s = sc[o], bb = bi[o];
        float4 r;
        r.x = fmaxf(fmaf(acc[i][0], s, bb), 0.f);
        r.y = fmaxf(fmaf(acc[i][1], s, bb), 0.f);
        r.z = fmaxf(fmaf(acc[i][2], s, bb), 0.f);
        r.w = fmaxf(fmaf(acc[i][3], s, bb), 0.f);
        *reinterpret_cast<float4*>(&dst[((size_t)(b * CDIM + o)) * NPIX + n0 + 4 * tn]) = r;
    }
}

// ---------------------------------------------------------------------------
// Flash attention (fp32): per block: one batch b, one 64-row q-tile.
// sim[q,k] = (1/16) * sum_c Q[c,q] K[c,k]; online softmax over k;
// O[q,c] = sum_k P[q,k] V[c,k]; out[b][c][q] = O[q,c] / l[q].
// grid (N/64, B) = 256 blocks, 512 threads, ~138 KB LDS -> 1 block/CU.
// ---------------------------------------------------------------------------
__global__ __launch_bounds__(512) void flash_kernel(
    const float* __restrict__ Q, const float* __restrict__ K,
    const float* __restrict__ V, float* __restrict__ out)
{
    const int qb = blockIdx.x * 64;   // q-tile base
    const int b  = blockIdx.y;

    __shared__ float Qall[CDIM][68];  // whole q-tile: [c][q]
    __shared__ float Ks[32][132];     // K chunk: [c][k]
    __shared__ float Pp[64][133];     // P tile: [q][k], pad 133 -> conflict-free PV reads
    __shared__ float Vs[16][257];     // V chunk transposed: [k][c]
    __shared__ float m_s[64], l_s[64], r_s[64];

    const int t = threadIdx.x;

    // S-phase mapping: 4q x 4k per thread (64 x 128 tile, 512 threads)
    const int s_q0 = (t >> 5) * 4;    // 0..60
    const int s_k0 = (t & 31) * 4;    // 0..124
    // PV mapping: 4q x 8c per thread (64 x 256 tile)
    const int p_q0 = (t & 15) * 4;    // 0..60
    const int p_c0 = (t >> 4) * 8;    // 0..248

    if (t < 64) { m_s[t] = -INFINITY; l_s[t] = 0.f; }

    // stage the whole Q tile once: 256 c-rows x 64 q
    {
        const int c    = t >> 1;
        const int qoff = (t & 1) * 32;
        const float* src = &Q[((size_t)(b * CDIM + c)) * NPIX + qb + qoff];
#pragma unroll
        for (int v = 0; v < 8; ++v)
            *reinterpret_cast<float4*>(&Qall[c][qoff + 4 * v]) =
                *reinterpret_cast<const float4*>(&src[4 * v]);
    }

    float O[4][8];
#pragma unroll
    for (int i = 0; i < 4; ++i)
#pragma unroll
        for (int j = 0; j < 8; ++j) O[i][j] = 0.f;

    __syncthreads();

    const float scl = 0.0625f;  // C^-0.5 = 1/16

    for (int kt = 0; kt < NPIX; kt += 128) {
        // ---------------- S = Q^T K over this 128-wide k-tile ----------------
        float s[4][4];
#pragma unroll
        for (int i = 0; i < 4; ++i)
#pragma unroll
            for (int j = 0; j < 4; ++j) s[i][j] = 0.f;

        for (int c0 = 0; c0 < CDIM; c0 += 32) {
            const int ci   = t >> 4;          // 0..31
            const int koff = (t & 15) * 8;    // 0..120
            const float* ksrc = &K[((size_t)(b * CDIM + c0 + ci)) * NPIX + kt + koff];
            float4 k0 = *reinterpret_cast<const float4*>(&ksrc[0]);
            float4 k1 = *reinterpret_cast<const float4*>(&ksrc[4]);
            __syncthreads();  // prev compute done before overwriting Ks
            *reinterpret_cast<float4*>(&Ks[ci][koff])     = k0;
            *reinterpret_cast<float4*>(&Ks[ci][koff + 4]) = k1;
            __syncthreads();
#pragma unroll
            for (int cc = 0; cc < 32; ++cc) {
                float4 qv = *reinterpret_cast<const float4*>(&Qall[c0 + cc][s_q0]);
                float4 kv = *reinterpret_cast<const float4*>(&Ks[cc][s_k0]);
                float qa[4] = {qv.x, qv.y, qv.z, qv.w};
                float ka[4] = {kv.x, kv.y, kv.z, kv.w};
#pragma unroll
                for (int i = 0; i < 4; ++i)
#pragma unroll
                    for (int j = 0; j < 4; ++j)
                        s[i][j] = fmaf(qa[i], ka[j], s[i][j]);
            }
        }

        // ---------------- online softmax (rows live in one 32-lane group) ----
        float mx[4];
#pragma unroll
        for (int i = 0; i < 4; ++i) {
            s[i][0] *= scl; s[i][1] *= scl; s[i][2] *= scl; s[i][3] *= scl;
            mx[i] = fmaxf(fmaxf(s[i][0], s[i][1]), fmaxf(s[i][2], s[i][3]));
        }
#pragma unroll
        for (int d = 1; d < 32; d <<= 1)
#pragma unroll
            for (int i = 0; i < 4; ++i) mx[i] = fmaxf(mx[i], __shfl_xor(mx[i], d, 64));

        float newm[4], resc[4], rs[4];
#pragma unroll
        for (int i = 0; i < 4; ++i) {
            const float mo = m_s[s_q0 + i];
            newm[i] = fmaxf(mo, mx[i]);
            resc[i] = __expf(mo - newm[i]);   // -inf-start -> 0, correct
            float r0 = 0.f;
#pragma unroll
            for (int j = 0; j < 4; ++j) { s[i][j] = __expf(s[i][j] - newm[i]); r0 += s[i][j]; }
            rs[i] = r0;
        }
#pragma unroll
        for (int d = 1; d < 32; d <<= 1)
#pragma unroll
            for (int i = 0; i < 4; ++i) rs[i] += __shfl_xor(rs[i], d, 64);

        if ((t & 31) == 0) {
#pragma unroll
            for (int i = 0; i < 4; ++i) {
                const int q = s_q0 + i;
                m_s[q] = newm[i];
                l_s[q] = l_s[q] * resc[i] + rs[i];
                r_s[q] = resc[i];
            }
        }
#pragma unroll
        for (int i = 0; i < 4; ++i)
#pragma unroll
            for (int j = 0; j < 4; ++j) Pp[s_q0 + i][s_k0 + j] = s[i][j];
        __syncthreads();

        // ---------------- PV: O[q,c] += P[q,k] V[c,k] ------------------------
#pragma unroll
        for (int i = 0; i < 4; ++i) {
            const float f = r_s[p_q0 + i];
#pragma unroll
            for (int j = 0; j < 8; ++j) O[i][j] *= f;
        }

        for (int sub = 0; sub < 8; ++sub) {
            const int c  = t >> 1;
            const int ko = (t & 1) * 8;
            const float* vsrc =
                &V[((size_t)(b * CDIM + c)) * NPIX + kt + sub * 16 + ko];
            float4 v0 = *reinterpret_cast<const float4*>(&vsrc[0]);
            float4 v1 = *reinterpret_cast<const float4*>(&vsrc[4]);
            __syncthreads();  // prev sub's compute done before overwriting Vs
            Vs[ko + 0][c] = v0.x; Vs[ko + 1][c] = v0.y;
            Vs[ko + 2][c] = v0.z; Vs[ko + 3][c] = v0.w;
            Vs[ko + 4][c] = v1.x; Vs[ko + 5][c] = v1.y;
            Vs[ko + 6][c] = v1.z; Vs[ko + 7][c] = v1.w;
            __syncthreads();
#pragma unroll
            for (int kk = 0; kk < 16; ++kk) {
                const int ka = sub * 16 + kk;
                float pv[4];
#pragma unroll
                for (int i = 0; i < 4; ++i) pv[i] = Pp[p_q0 + i][ka];
                float4 va = *reinterpret_cast<const float4*>(&Vs[kk][p_c0]);
                float4 vb = *reinterpret_cast<const float4*>(&Vs[kk][p_c0 + 4]);
                float vv[8] = {va.x, va.y, va.z, va.w, vb.x, vb.y, vb.z, vb.w};
#pragma unroll
                for (int i = 0; i < 4; ++i)
#pragma unroll
                    for (int j = 0; j < 8; ++j)
                        O[i][j] = fmaf(pv[i], vv[j], O[i][j]);
            }
        }
    }

    // ---------------- epilogue: divide by l, store [b][c][q] -----------------
#pragma unroll
    for (int i = 0; i < 4; ++i) {
        const float inv = 1.f / l_s[p_q0 + i];
#pragma unroll
        for (int j = 0; j < 8; ++j)
            out[((size_t)(b * CDIM + p_c0 + j)) * NPIX + qb + p_q0 + i] = O[i][j] * inv;
    }
}

// ---------------------------------------------------------------------------
extern "C" void kernel_launch(void* const* d_in, const int* in_sizes, int n_in,
                              void* d_out, int out_size, void* d_ws, size_t ws_size,
                              hipStream_t stream)
{
    const float* qf = (const float*)d_in[0];
    const float* kf = (const float*)d_in[1];
    const float* Wq = (const float*)d_in[2];
    const float* Wk = (const float*)d_in[3];
    const float* Wv = (const float*)d_in[4];
    const float* sq = (const float*)d_in[5];
    const float* bq = (const float*)d_in[6];
    const float* sk = (const float*)d_in[7];
    const float* bk = (const float*)d_in[8];
    const float* sv = (const float*)d_in[9];
    const float* bv = (const float*)d_in[10];
    float* out = (float*)d_out;

    // workspace: Q, K, V each [B][C][N] fp32 = 16 MB -> 48 MB total
    const size_t plane = (size_t)BATCH * CDIM * NPIX;
    float* ws = (float*)d_ws;
    float* Q = ws;
    float* K = ws + plane;
    float* V = ws + 2 * plane;

    dim3 gp(NPIX / 64, CDIM / 64, 3 * BATCH);
    proj_kernel<<<gp, 256, 0, stream>>>(qf, kf, Wq, Wk, Wv, sq, bq, sk, bk, sv, bv, Q, K, V);

    dim3 gf(NPIX / 64, BATCH);
    flash_kernel<<<gf, 512, 0, stream>>>(Q, K, V, out);
}

// Round 3
// 590.339 us; speedup vs baseline: 2.5368x; 2.5368x over previous
//
#include <hip/hip_runtime.h>
#include <math.h>

#define CDIM 256
#define NPIX 4096
#define BATCH 4
#define QB 64
#define KB 32

typedef __attribute__((ext_vector_type(8))) short short8;
typedef __attribute__((ext_vector_type(4))) float f32x4;
#define MFMA(a, b, c) __builtin_amdgcn_mfma_f32_16x16x32_bf16((a), (b), (c), 0, 0, 0)

__device__ __forceinline__ unsigned short f2bf(float f) {
    union { float f; unsigned int u; } v; v.f = f;
    unsigned int u = v.u;
    return (unsigned short)((u + 0x7FFFu + ((u >> 16) & 1u)) >> 16);
}
__device__ __forceinline__ float bf2f(unsigned short h) {
    union { unsigned int u; float f; } v; v.u = ((unsigned int)h) << 16;
    return v.f;
}

// ---------------------------------------------------------------------------
// Projection: y = relu(scale*(W x) + bias), emitted as bf16 hi/lo planes.
// which 0 (Q) / 1 (K): dst layout [B][N][C]  (transposed, for MFMA A/B frags)
// which 2 (V):         dst layout [B][C][N]  (natural, for MFMA A frags)
// grid (N/64, C/64, 3*B), block 256. Tile 64(o) x 64(n), K-chunk 32.
// ---------------------------------------------------------------------------
__global__ __launch_bounds__(256) void proj_kernel(
    const float* __restrict__ qf, const float* __restrict__ kf,
    const float* __restrict__ Wq, const float* __restrict__ Wk, const float* __restrict__ Wv,
    const float* __restrict__ sq, const float* __restrict__ bq,
    const float* __restrict__ sk, const float* __restrict__ bk,
    const float* __restrict__ sv, const float* __restrict__ bv,
    unsigned short* __restrict__ Qth, unsigned short* __restrict__ Qtl,
    unsigned short* __restrict__ Kth, unsigned short* __restrict__ Ktl,
    unsigned short* __restrict__ Vh,  unsigned short* __restrict__ Vl)
{
    const int n0 = blockIdx.x * 64;
    const int o0 = blockIdx.y * 64;
    const int z  = blockIdx.z;
    const int which = z % 3;
    const int b     = z / 3;

    const float* W; const float* x; const float* sc; const float* bi;
    unsigned short* dh; unsigned short* dl;
    if (which == 0)      { W = Wq; x = qf; sc = sq; bi = bq; dh = Qth; dl = Qtl; }
    else if (which == 1) { W = Wk; x = kf; sc = sk; bi = bk; dh = Kth; dl = Ktl; }
    else                 { W = Wv; x = kf; sc = sv; bi = bv; dh = Vh;  dl = Vl;  }

    __shared__ float Wt[32][68];
    __shared__ float Xt[32][68];

    const int t  = threadIdx.x;
    const int to = t >> 4;
    const int tn = t & 15;

    const int w_oi  = t >> 2;
    const int w_cc0 = (t & 3) * 8;
    const int x_ci  = t >> 3;
    const int x_no  = (t & 7) * 8;

    float acc[4][4];
#pragma unroll
    for (int i = 0; i < 4; ++i)
#pragma unroll
        for (int j = 0; j < 4; ++j) acc[i][j] = 0.f;

    for (int c0 = 0; c0 < CDIM; c0 += 32) {
        float4 wv[2], xv[2];
#pragma unroll
        for (int v = 0; v < 2; ++v)
            wv[v] = *reinterpret_cast<const float4*>(
                &W[(size_t)(o0 + w_oi) * CDIM + c0 + w_cc0 + 4 * v]);
#pragma unroll
        for (int v = 0; v < 2; ++v)
            xv[v] = *reinterpret_cast<const float4*>(
                &x[((size_t)(b * CDIM + c0 + x_ci)) * NPIX + n0 + x_no + 4 * v]);
        __syncthreads();
#pragma unroll
        for (int v = 0; v < 2; ++v) {
            Wt[w_cc0 + 4 * v + 0][w_oi] = wv[v].x;
            Wt[w_cc0 + 4 * v + 1][w_oi] = wv[v].y;
            Wt[w_cc0 + 4 * v + 2][w_oi] = wv[v].z;
            Wt[w_cc0 + 4 * v + 3][w_oi] = wv[v].w;
            *reinterpret_cast<float4*>(&Xt[x_ci][x_no + 4 * v]) = xv[v];
        }
        __syncthreads();
#pragma unroll
        for (int cc = 0; cc < 32; ++cc) {
            float4 a = *reinterpret_cast<const float4*>(&Wt[cc][4 * to]);
            float4 c = *reinterpret_cast<const float4*>(&Xt[cc][4 * tn]);
            float wa[4] = {a.x, a.y, a.z, a.w};
            float xa[4] = {c.x, c.y, c.z, c.w};
#pragma unroll
            for (int i = 0; i < 4; ++i)
#pragma unroll
                for (int j = 0; j < 4; ++j)
                    acc[i][j] = fmaf(wa[i], xa[j], acc[i][j]);
        }
        __syncthreads();
    }

    unsigned short hi[4][4], lo[4][4];
#pragma unroll
    for (int i = 0; i < 4; ++i) {
        const int o = o0 + 4 * to + i;
        const float s = sc[o], bb = bi[o];
#pragma unroll
        for (int j = 0; j < 4; ++j) {
            float val = fmaxf(fmaf(acc[i][j], s, bb), 0.f);
            unsigned short h = f2bf(val);
            hi[i][j] = h;
            lo[i][j] = f2bf(val - bf2f(h));
        }
    }

    if (which < 2) {
        // [b][n][o]
#pragma unroll
        for (int j = 0; j < 4; ++j) {
            const size_t addr = ((size_t)b * NPIX + n0 + 4 * tn + j) * CDIM + o0 + 4 * to;
            ushort4 h4 = make_ushort4(hi[0][j], hi[1][j], hi[2][j], hi[3][j]);
            ushort4 l4 = make_ushort4(lo[0][j], lo[1][j], lo[2][j], lo[3][j]);
            *reinterpret_cast<ushort4*>(&dh[addr]) = h4;
            *reinterpret_cast<ushort4*>(&dl[addr]) = l4;
        }
    } else {
        // [b][o][n]
#pragma unroll
        for (int i = 0; i < 4; ++i) {
            const size_t addr = ((size_t)b * CDIM + o0 + 4 * to + i) * NPIX + n0 + 4 * tn;
            ushort4 h4 = make_ushort4(hi[i][0], hi[i][1], hi[i][2], hi[i][3]);
            ushort4 l4 = make_ushort4(lo[i][0], lo[i][1], lo[i][2], lo[i][3]);
            *reinterpret_cast<ushort4*>(&dh[addr]) = h4;
            *reinterpret_cast<ushort4*>(&dl[addr]) = l4;
        }
    }
}

// ---------------------------------------------------------------------------
// MFMA flash attention, split-bf16 (hi/lo) for ~fp32 accuracy.
// Block: one batch b, 64 q-rows. 8 waves, 512 threads.
// S phase: wave w: m-frag smq=w&3 (16 q), k-half snk=w>>2 (16 of 32 keys).
// PV phase: wave w: q-frag pqf=w&3, c-half pch=w>>2 (8 c-frags of 16).
// ---------------------------------------------------------------------------
__global__ __launch_bounds__(512, 2) void flash_kernel(
    const unsigned short* __restrict__ Qth, const unsigned short* __restrict__ Qtl,
    const unsigned short* __restrict__ Kth, const unsigned short* __restrict__ Ktl,
    const unsigned short* __restrict__ Vh,  const unsigned short* __restrict__ Vl,
    float* __restrict__ out)
{
    // XCD-grouped mapping: each XCD gets 32 consecutive virtual blocks (same batch)
    const int bid  = blockIdx.x;
    const int virt = ((bid & 7) << 5) | (bid >> 3);
    const int b    = virt >> 6;
    const int qb   = (virt & 63) * QB;

    __shared__ unsigned short Ksh[KB][264], Ksl[KB][264];   // [k][c], pad->528B rows
    __shared__ unsigned short Vsh[CDIM][40], Vsl[CDIM][40]; // [c][k], pad->80B rows
    __shared__ unsigned short Phs[QB][40],  Pls[QB][40];    // [q][k]
    __shared__ float Msh[2][QB], Ssh2[2][QB], Rsh[QB], Linv[QB];

    const int t    = threadIdx.x;
    const int w    = t >> 6;
    const int lane = t & 63;
    const int g    = lane >> 4;
    const int li   = lane & 15;

    const int smq = w & 3, snk = w >> 2;   // S roles
    const int pqf = w & 3, pch = w >> 2;   // PV roles

    // staging coords
    const int krow = t >> 4, kcol = (t & 15) * 16;  // K tile: 32 x 256
    const int vrow = t >> 1, vcol = (t & 1) * 16;   // V tile: 256 x 32

    // ---- Q fragments in registers for the whole k-loop ----
    short8 qh[8], ql[8];
    {
        const size_t qbase = ((size_t)b * NPIX + qb + smq * 16 + li) * CDIM + g * 8;
#pragma unroll
        for (int cs = 0; cs < 8; ++cs) {
            qh[cs] = *reinterpret_cast<const short8*>(&Qth[qbase + cs * 32]);
            ql[cs] = *reinterpret_cast<const short8*>(&Qtl[qbase + cs * 32]);
        }
    }

    f32x4 O[8];
#pragma unroll
    for (int fi = 0; fi < 8; ++fi) O[fi] = (f32x4){0.f, 0.f, 0.f, 0.f};

    float m_run[4], l_run[4];
#pragma unroll
    for (int r = 0; r < 4; ++r) { m_run[r] = -INFINITY; l_run[r] = 0.f; }

    const float scl = 0.0625f;  // C^-0.5

    // prefetch registers for one K/V tile
    uint4 rKh0, rKh1, rKl0, rKl1, rVh0, rVh1, rVl0, rVl1;
    const size_t kgbase = ((size_t)b * NPIX + krow) * CDIM + kcol;
    const size_t vgbase = ((size_t)b * CDIM + vrow) * NPIX + vcol;

    {
        const size_t ka = kgbase;  // kt = 0
        rKh0 = *reinterpret_cast<const uint4*>(&Kth[ka]);
        rKh1 = *reinterpret_cast<const uint4*>(&Kth[ka + 8]);
        rKl0 = *reinterpret_cast<const uint4*>(&Ktl[ka]);
        rKl1 = *reinterpret_cast<const uint4*>(&Ktl[ka + 8]);
        const size_t va = vgbase;
        rVh0 = *reinterpret_cast<const uint4*>(&Vh[va]);
        rVh1 = *reinterpret_cast<const uint4*>(&Vh[va + 8]);
        rVl0 = *reinterpret_cast<const uint4*>(&Vl[va]);
        rVl1 = *reinterpret_cast<const uint4*>(&Vl[va + 8]);
    }

    const int NT = NPIX / KB;  // 128
    for (int it = 0; it < NT; ++it) {
        // ---- write staged tile to LDS ----
        *reinterpret_cast<uint4*>(&Ksh[krow][kcol])     = rKh0;
        *reinterpret_cast<uint4*>(&Ksh[krow][kcol + 8]) = rKh1;
        *reinterpret_cast<uint4*>(&Ksl[krow][kcol])     = rKl0;
        *reinterpret_cast<uint4*>(&Ksl[krow][kcol + 8]) = rKl1;
        *reinterpret_cast<uint4*>(&Vsh[vrow][vcol])     = rVh0;
        *reinterpret_cast<uint4*>(&Vsh[vrow][vcol + 8]) = rVh1;
        *reinterpret_cast<uint4*>(&Vsl[vrow][vcol])     = rVl0;
        *reinterpret_cast<uint4*>(&Vsl[vrow][vcol + 8]) = rVl1;
        __syncthreads();  // B0

        // ---- S = Q^T K  (split: qh*kh + ql*kh + qh*kl) ----
        f32x4 sacc = (f32x4){0.f, 0.f, 0.f, 0.f};
#pragma unroll
        for (int cs = 0; cs < 8; ++cs) {
            short8 kbh = *reinterpret_cast<const short8*>(&Ksh[snk * 16 + li][cs * 32 + g * 8]);
            short8 kbl = *reinterpret_cast<const short8*>(&Ksl[snk * 16 + li][cs * 32 + g * 8]);
            sacc = MFMA(qh[cs], kbh, sacc);
            sacc = MFMA(ql[cs], kbh, sacc);
            sacc = MFMA(qh[cs], kbl, sacc);
        }

        // ---- prefetch next tile's K/V into registers (issued here so the
        //      ~global-load latency hides under softmax + PV compute) ----
        {
            const int ktn = (it + 1 < NT) ? (it + 1) * KB : 0;
            const size_t ka = kgbase + (size_t)ktn * CDIM;
            rKh0 = *reinterpret_cast<const uint4*>(&Kth[ka]);
            rKh1 = *reinterpret_cast<const uint4*>(&Kth[ka + 8]);
            rKl0 = *reinterpret_cast<const uint4*>(&Ktl[ka]);
            rKl1 = *reinterpret_cast<const uint4*>(&Ktl[ka + 8]);
            const size_t va = vgbase + ktn;
            rVh0 = *reinterpret_cast<const uint4*>(&Vh[va]);
            rVh1 = *reinterpret_cast<const uint4*>(&Vh[va + 8]);
            rVl0 = *reinterpret_cast<const uint4*>(&Vl[va]);
            rVl1 = *reinterpret_cast<const uint4*>(&Vl[va + 8]);
        }

        // ---- online softmax: rows q = smq*16 + g*4 + r, cols k = snk*16 + li
        float sv[4], mx[4];
#pragma unroll
        for (int r = 0; r < 4; ++r) { sv[r] = sacc[r] * scl; mx[r] = sv[r]; }
#pragma unroll
        for (int d = 1; d < 16; d <<= 1)
#pragma unroll
            for (int r = 0; r < 4; ++r) mx[r] = fmaxf(mx[r], __shfl_xor(mx[r], d, 64));

        if (li == 0) {
#pragma unroll
            for (int r = 0; r < 4; ++r) Msh[snk][smq * 16 + g * 4 + r] = mx[r];
        }
        __syncthreads();  // B1

        float p[4], resc[4], psum[4];
#pragma unroll
        for (int r = 0; r < 4; ++r) {
            const int q = smq * 16 + g * 4 + r;
            const float mt = fmaxf(Msh[0][q], Msh[1][q]);
            const float mn = fmaxf(m_run[r], mt);
            resc[r] = __expf(m_run[r] - mn);
            m_run[r] = mn;
            p[r] = __expf(sv[r] - mn);
            psum[r] = p[r];
        }
#pragma unroll
        for (int d = 1; d < 16; d <<= 1)
#pragma unroll
            for (int r = 0; r < 4; ++r) psum[r] += __shfl_xor(psum[r], d, 64);

#pragma unroll
        for (int r = 0; r < 4; ++r) {
            const int q = smq * 16 + g * 4 + r;
            unsigned short ph = f2bf(p[r]);
            Phs[q][snk * 16 + li] = ph;
            Pls[q][snk * 16 + li] = f2bf(p[r] - bf2f(ph));
        }
        if (li == 0) {
#pragma unroll
            for (int r = 0; r < 4; ++r) {
                const int q = smq * 16 + g * 4 + r;
                Ssh2[snk][q] = psum[r];
                if (snk == 0) Rsh[q] = resc[r];
            }
        }
        __syncthreads();  // B2

        // ---- l update (kept redundantly in both S-waves sharing smq) ----
#pragma unroll
        for (int r = 0; r < 4; ++r) {
            const int q = smq * 16 + g * 4 + r;
            l_run[r] = l_run[r] * resc[r] + Ssh2[0][q] + Ssh2[1][q];
        }

        // ---- PV: O[c][q] += V[c][k] P[q][k]  (split: vh*ph + vl*ph + vh*pl)
        const float rf = Rsh[pqf * 16 + li];
        short8 pa = *reinterpret_cast<const short8*>(&Phs[pqf * 16 + li][g * 8]);
        short8 pb = *reinterpret_cast<const short8*>(&Pls[pqf * 16 + li][g * 8]);
#pragma unroll
        for (int fi = 0; fi < 8; ++fi) {
            O[fi] = O[fi] * rf;
            const int crow = (pch * 8 + fi) * 16 + li;
            short8 va = *reinterpret_cast<const short8*>(&Vsh[crow][g * 8]);
            short8 vb = *reinterpret_cast<const short8*>(&Vsl[crow][g * 8]);
            O[fi] = MFMA(va, pa, O[fi]);
            O[fi] = MFMA(vb, pa, O[fi]);
            O[fi] = MFMA(va, pb, O[fi]);
        }
        __syncthreads();  // B3 (protects Ks/Vs/P overwrite next iteration)
    }

    // ---- epilogue ----
    if (snk == 0 && li == 0) {
#pragma unroll
        for (int r = 0; r < 4; ++r)
            Linv[smq * 16 + g * 4 + r] = 1.0f / l_run[r];
    }
    __syncthreads();

    const float linv = Linv[pqf * 16 + li];
#pragma unroll
    for (int fi = 0; fi < 8; ++fi) {
#pragma unroll
        for (int r = 0; r < 4; ++r) {
            const int c = (pch * 8 + fi) * 16 + g * 4 + r;
            out[((size_t)(b * CDIM + c)) * NPIX + qb + pqf * 16 + li] = O[fi][r] * linv;
        }
    }
}

// ---------------------------------------------------------------------------
extern "C" void kernel_launch(void* const* d_in, const int* in_sizes, int n_in,
                              void* d_out, int out_size, void* d_ws, size_t ws_size,
                              hipStream_t stream)
{
    const float* qf = (const float*)d_in[0];
    const float* kf = (const float*)d_in[1];
    const float* Wq = (const float*)d_in[2];
    const float* Wk = (const float*)d_in[3];
    const float* Wv = (const float*)d_in[4];
    const float* sq = (const float*)d_in[5];
    const float* bq = (const float*)d_in[6];
    const float* sk = (const float*)d_in[7];
    const float* bk = (const float*)d_in[8];
    const float* sv = (const float*)d_in[9];
    const float* bv = (const float*)d_in[10];
    float* out = (float*)d_out;

    // workspace: 6 bf16 planes of [B][*][*] = 4M elements (8 MB) each -> 48 MB
    const size_t plane = (size_t)BATCH * CDIM * NPIX;
    unsigned short* ws = (unsigned short*)d_ws;
    unsigned short* Qth = ws;
    unsigned short* Qtl = ws + plane;
    unsigned short* Kth = ws + 2 * plane;
    unsigned short* Ktl = ws + 3 * plane;
    unsigned short* Vh  = ws + 4 * plane;
    unsigned short* Vl  = ws + 5 * plane;

    dim3 gp(NPIX / 64, CDIM / 64, 3 * BATCH);
    proj_kernel<<<gp, 256, 0, stream>>>(qf, kf, Wq, Wk, Wv, sq, bq, sk, bk, sv, bv,
                                        Qth, Qtl, Kth, Ktl, Vh, Vl);

    flash_kernel<<<dim3(256), 512, 0, stream>>>(Qth, Qtl, Kth, Ktl, Vh, Vl, out);
}